// Round 5
// baseline (960.779 us; speedup 1.0000x reference)
//
#include <hip/hip_runtime.h>
#include <hip/hip_bf16.h>
#include <math.h>

// ---------------------------------------------------------------------------
// YatNMN: out = scale * ( y^2/(||x||^2+||w||^2-2y+eps) + bias ), y = x@W
// x:[16384,2048] f32, W:[2048,8192] f32, out f32 [16384,8192].
// R5 = R4 + one-phase-ahead register prefetch (ds_reads for phase p+1 issued
// in phase p -> lgkmcnt hides under MFMA; A/B frag regs double-buffered) and
// fused ||w||^2 partials into the kT kernel.
// Workspace: [0) xbf 64MB | [64M) ktb 32MB | xs | ks | kpart (<=2MB)
// ---------------------------------------------------------------------------

#define EPS_F (1.0f / 137.0f)
#define M_DIM 16384
#define N_DIM 8192
#define K_DIM 2048

typedef __attribute__((ext_vector_type(8))) short short8;
typedef __attribute__((ext_vector_type(4))) float f32x4;

__device__ __forceinline__ unsigned short f2bf(float f) {
  unsigned int u = __float_as_uint(f);
  u += 0x7fffu + ((u >> 16) & 1u);
  return (unsigned short)(u >> 16);
}

typedef __attribute__((address_space(1))) const unsigned int as1_cuint;
typedef __attribute__((address_space(3))) unsigned int as3_uint;

__device__ __forceinline__ void gload16(const void* g, void* lds_wave_base) {
  __builtin_amdgcn_global_load_lds((as1_cuint*)g, (as3_uint*)lds_wave_base, 16, 0, 0);
}

// --------------------------- prologue kernels ------------------------------

__global__ __launch_bounds__(256) void k_conv_x(const float* __restrict__ x,
                                                unsigned short* __restrict__ xbf,
                                                float* __restrict__ xs) {
  const int row = blockIdx.x;
  const int t = threadIdx.x;
  const float4* xr = (const float4*)(x + (size_t)row * K_DIM);
  ushort4* orow = (ushort4*)(xbf + (size_t)row * K_DIM);
  float s = 0.f;
#pragma unroll
  for (int i = 0; i < 2; ++i) {
    float4 v = xr[t + i * 256];
    s += v.x * v.x + v.y * v.y + v.z * v.z + v.w * v.w;
    ushort4 o;
    o.x = f2bf(v.x); o.y = f2bf(v.y); o.z = f2bf(v.z); o.w = f2bf(v.w);
    orow[t + i * 256] = o;
  }
#pragma unroll
  for (int off = 32; off > 0; off >>= 1) s += __shfl_down(s, off, 64);
  __shared__ float red[4];
  if ((t & 63) == 0) red[t >> 6] = s;
  __syncthreads();
  if (t == 0) xs[row] = red[0] + red[1] + red[2] + red[3];
}

// W [K][N] f32 -> W^T [N][K] bf16, fused per-(32-row-block, col) ssq partials.
__global__ __launch_bounds__(256) void k_conv_kT_fused(const float* __restrict__ w,
                                                       unsigned short* __restrict__ bt,
                                                       float* __restrict__ kpart) {
  __shared__ float tile[32][33];
  __shared__ float psum[8][33];
  const int tx = threadIdx.x;
  const int ty = threadIdx.y;
  const int n0 = blockIdx.x * 32;
  const int k0 = blockIdx.y * 32;
  float ss = 0.f;
#pragma unroll
  for (int j = 0; j < 32; j += 8) {
    float v = w[(size_t)(k0 + ty + j) * N_DIM + n0 + tx];
    tile[ty + j][tx] = v;
    ss += v * v;
  }
  psum[ty][tx] = ss;
  __syncthreads();
#pragma unroll
  for (int j = 0; j < 32; j += 8)
    bt[(size_t)(n0 + ty + j) * K_DIM + k0 + tx] = f2bf(tile[tx][ty + j]);
  if (ty == 0) {
    float s = 0.f;
#pragma unroll
    for (int r = 0; r < 8; ++r) s += psum[r][tx];
    kpart[(size_t)(k0 >> 5) * N_DIM + n0 + tx] = s;
  }
}

// fallback (small ws): plain transpose + separate stripe partials
__global__ __launch_bounds__(256) void k_conv_kT(const float* __restrict__ w,
                                                 unsigned short* __restrict__ bt) {
  __shared__ float tile[32][33];
  const int tx = threadIdx.x;
  const int ty = threadIdx.y;
  const int n0 = blockIdx.x * 32;
  const int k0 = blockIdx.y * 32;
#pragma unroll
  for (int j = 0; j < 32; j += 8)
    tile[ty + j][tx] = w[(size_t)(k0 + ty + j) * N_DIM + n0 + tx];
  __syncthreads();
#pragma unroll
  for (int j = 0; j < 32; j += 8)
    bt[(size_t)(n0 + ty + j) * K_DIM + k0 + tx] = f2bf(tile[tx][ty + j]);
}

__global__ __launch_bounds__(256) void k_ksq_part(const float* __restrict__ w,
                                                  float* __restrict__ kpart) {
  const int col = blockIdx.x * 256 + threadIdx.x;
  const int kb = blockIdx.y;
  float s = 0.f;
#pragma unroll 4
  for (int k = kb * 128; k < kb * 128 + 128; ++k) {
    float v = w[(size_t)k * N_DIM + col];
    s += v * v;
  }
  kpart[kb * N_DIM + col] = s;
}

__global__ __launch_bounds__(256) void k_ksq_fin(const float* __restrict__ kpart,
                                                 float* __restrict__ ks, int nkb) {
  const int col = blockIdx.x * 256 + threadIdx.x;
  float s = 0.f;
  for (int kb = 0; kb < nkb; ++kb) s += kpart[(size_t)kb * N_DIM + col];
  ks[col] = s;
}

// ------------------------------- GEMM 256x256 8-phase ----------------------
// A: xbf [M][K] bf16.  B: ktb [N][K] bf16.  8 waves: wr=wid>>2 (M), wc=wid&3.
// LDS: sA[2][256][128B], sB[2][256][128B] = 128 KiB, XOR swizzle
//   byte_col ^= (row&7)<<4 on ds_read; inverse on the global_load_lds source.
// One-phase-ahead prefetch: phase p ds_reads regs consumed by phase p+1's
// MFMA; A-frag sets aX/aY and B-frag sets bX/bY alternate.
// Staging (2 gload_lds/phase): ph0 completes T1(buf1); ph1-4 stage T2(buf0);
// ph5-7 stage T3(buf1 stripes 0-2). vmcnt(4) at end of ph2 (T1 landed, read
// at ph3) and ph6 (T2 landed, read at ph7); barrier after makes it
// cross-wave. Never drained to 0 inside the loop.

#define MFMA_OP(d, va, vb) \
  d = __builtin_amdgcn_mfma_f32_16x16x32_bf16(va, vb, d, 0, 0, 0)

#define FENCE asm volatile("" ::: "memory")
#define BAR do { FENCE; __builtin_amdgcn_s_barrier(); FENCE; } while (0)
#define VMCNT4 asm volatile("s_waitcnt vmcnt(4)" ::: "memory")
#define VMCNT6 asm volatile("s_waitcnt vmcnt(6)" ::: "memory")

__global__ __launch_bounds__(512, 2) void k_gemm(const unsigned short* __restrict__ A,
                                                 const unsigned short* __restrict__ B,
                                                 const float* __restrict__ xs,
                                                 const float* __restrict__ ks,
                                                 const float* __restrict__ bias,
                                                 const float* __restrict__ alpha,
                                                 float* __restrict__ out) {
  __shared__ __align__(16) char lds[131072];
  char* sA = lds;
  char* sB = lds + 65536;

  const int t = threadIdx.x;
  const int lane = t & 63;
  const int wid = t >> 6;
  const int wr = wid >> 2;  // 0..1 (M)
  const int wc = wid & 3;   // 0..3 (N)
  const int lr = lane & 15;
  const int kh = lane >> 4;
  const int swz = (lr & 7) << 4;

  // 2D-chunked XCD swizzle (bijective: 2048 = 8 xcd * 8 chunks * 32).
  const int bid = blockIdx.x;
  const int xcd = bid & 7;
  const int sub = bid >> 3;
  const int c   = sub >> 5;
  const int tm = ((xcd >> 1) << 4) + ((c >> 1) << 2) + ((sub >> 3) & 3);
  const int tn = ((xcd & 1) << 4) + ((c & 1) << 3) + (sub & 7);
  const size_t rowM0 = (size_t)tm * 256;
  const size_t colN0 = (size_t)tn * 256;

  const int l8 = lane >> 3;
  const int col16 = (lane & 7) ^ (l8 & 7);
  const int rA_base = (wid < 4) ? wid * 8 : 128 + (wid - 4) * 8;
  const unsigned short* gA0 = A + (rowM0 + rA_base + l8) * K_DIM + col16 * 8;
  const unsigned short* gB0 = B + (colN0 + wid * 8 + l8) * K_DIM + col16 * 8;

#define STAGE_A(b, s, ko) \
  gload16(gA0 + (size_t)(s) * 32 * K_DIM + (ko), \
          sA + (b) * 32768 + (rA_base + (s) * 32) * 128)
#define STAGE_B(b, j, ko) \
  gload16(gB0 + (size_t)(j) * 64 * K_DIM + (ko), \
          sB + (b) * 32768 + ((j) * 64 + wid * 8) * 128)

#define RD_A(b, m, kk) \
  (*(const short8*)(sA + (b) * 32768 + (wr * 128 + (m) * 16 + lr) * 128 + \
                    (((kk) * 64 + kh * 16) ^ swz)))
#define RD_B(b, n, kk) \
  (*(const short8*)(sB + (b) * 32768 + (wc * 64 + (n) * 16 + lr) * 128 + \
                    (((kk) * 64 + kh * 16) ^ swz)))

  f32x4 acc[8][4] = {};
  // double-buffered fragment registers
  short8 aX0, aX1, aX2, aX3, aY0, aY1, aY2, aY3;
  short8 bX[8], bY[8];

// AS##0 = m_lo kk0, AS##1 = m_lo kk1, AS##2 = m_hi kk0, AS##3 = m_hi kk1
#define LOAD_A(AS, b, mb) do { \
  AS##0 = RD_A(b, mb, 0); AS##1 = RD_A(b, mb, 1); \
  AS##2 = RD_A(b, (mb)+1, 0); AS##3 = RD_A(b, (mb)+1, 1); \
} while (0)
// BS[n] = kk0, BS[4+n] = kk1
#define LOAD_B(BS, b) do { \
  BS[0] = RD_B(b, 0, 0); BS[1] = RD_B(b, 1, 0); BS[2] = RD_B(b, 2, 0); BS[3] = RD_B(b, 3, 0); \
  BS[4] = RD_B(b, 0, 1); BS[5] = RD_B(b, 1, 1); BS[6] = RD_B(b, 2, 1); BS[7] = RD_B(b, 3, 1); \
} while (0)

#define MFMA16(mb, AS, BS) do { \
  __builtin_amdgcn_s_setprio(1); \
  MFMA_OP(acc[mb][0], AS##0, BS[0]); MFMA_OP(acc[mb][1], AS##0, BS[1]); \
  MFMA_OP(acc[mb][2], AS##0, BS[2]); MFMA_OP(acc[mb][3], AS##0, BS[3]); \
  MFMA_OP(acc[(mb)+1][0], AS##2, BS[0]); MFMA_OP(acc[(mb)+1][1], AS##2, BS[1]); \
  MFMA_OP(acc[(mb)+1][2], AS##2, BS[2]); MFMA_OP(acc[(mb)+1][3], AS##2, BS[3]); \
  MFMA_OP(acc[mb][0], AS##1, BS[4]); MFMA_OP(acc[mb][1], AS##1, BS[5]); \
  MFMA_OP(acc[mb][2], AS##1, BS[6]); MFMA_OP(acc[mb][3], AS##1, BS[7]); \
  MFMA_OP(acc[(mb)+1][0], AS##3, BS[4]); MFMA_OP(acc[(mb)+1][1], AS##3, BS[5]); \
  MFMA_OP(acc[(mb)+1][2], AS##3, BS[6]); MFMA_OP(acc[(mb)+1][3], AS##3, BS[7]); \
  __builtin_amdgcn_s_setprio(0); \
} while (0)

  // prologue: T0 complete (8) -> buf0, T1 stripes 0-2 + B0-2 (6) -> buf1
  STAGE_A(0, 0, 0); STAGE_B(0, 0, 0);
  STAGE_A(0, 1, 0); STAGE_B(0, 1, 0);
  STAGE_A(0, 2, 0); STAGE_B(0, 2, 0);
  STAGE_A(0, 3, 0); STAGE_B(0, 3, 0);
  STAGE_A(1, 0, 64); STAGE_B(1, 0, 64);
  STAGE_A(1, 1, 64); STAGE_B(1, 1, 64);
  STAGE_A(1, 2, 64); STAGE_B(1, 2, 64);
  VMCNT6;  // T0's 8 landed (6 newer outstanding)
  BAR;
  // preload phase-0 consumables from buf0
  LOAD_B(bX, 0);
  LOAD_A(aX, 0, 0);

#pragma unroll 1
  for (int it = 0; it < 16; ++it) {
    const int kT1 = it * 128 + 64;                    // tile 2it+1 (real)
    const int kS0 = (it < 15) ? it * 128 + 128 : 0;   // tile 2it+2 (clamped)
    const int kS1 = (it < 15) ? it * 128 + 192 : 0;   // tile 2it+3 (clamped)
    // ph0: prefetch A m23 buf0; complete T1; MFMA m01 buf0
    LOAD_A(aY, 0, 2); STAGE_A(1, 3, kT1); STAGE_B(1, 3, kT1);
    BAR; MFMA16(0, aX, bX); BAR;
    // ph1
    LOAD_A(aX, 0, 4); STAGE_A(0, 0, kS0); STAGE_B(0, 0, kS0);
    BAR; MFMA16(2, aY, bX); BAR;
    // ph2 (+vmcnt: T1 fully landed for ph3's reads)
    LOAD_A(aY, 0, 6); STAGE_A(0, 1, kS0); STAGE_B(0, 1, kS0);
    BAR; MFMA16(4, aX, bX); VMCNT4; BAR;
    // ph3: prefetch B buf1 + A m01 buf1; MFMA m67 buf0
    LOAD_B(bY, 1); LOAD_A(aX, 1, 0); STAGE_A(0, 2, kS0); STAGE_B(0, 2, kS0);
    BAR; MFMA16(6, aY, bX); BAR;
    // ph4
    LOAD_A(aY, 1, 2); STAGE_A(0, 3, kS0); STAGE_B(0, 3, kS0);
    BAR; MFMA16(0, aX, bY); BAR;
    // ph5
    LOAD_A(aX, 1, 4); STAGE_A(1, 0, kS1); STAGE_B(1, 0, kS1);
    BAR; MFMA16(2, aY, bY); BAR;
    // ph6 (+vmcnt: T2 fully landed for ph7's reads)
    LOAD_A(aY, 1, 6); STAGE_A(1, 1, kS1); STAGE_B(1, 1, kS1);
    BAR; MFMA16(4, aX, bY); VMCNT4; BAR;
    // ph7: prefetch B buf0 (next tile) + A m01 buf0; MFMA m67 buf1
    LOAD_B(bX, 0); LOAD_A(aX, 0, 0); STAGE_A(1, 2, kS1); STAGE_B(1, 2, kS1);
    BAR; MFMA16(6, aY, bY); BAR;
  }

  asm volatile("s_waitcnt vmcnt(0)" ::: "memory");

  // fused Yat epilogue. C/D: col = lane&15 (N), row = (lane>>4)*4 + reg (M).
  const float scale = powf(sqrtf(8192.0f) / log1pf(8192.0f), alpha[0]);
#pragma unroll
  for (int m = 0; m < 8; ++m) {
#pragma unroll
    for (int r = 0; r < 4; ++r) {
      const size_t grow = rowM0 + wr * 128 + m * 16 + kh * 4 + r;
      const float xq = xs[grow];
      float* orow = out + grow * N_DIM;
#pragma unroll
      for (int n = 0; n < 4; ++n) {
        const int gcol = (int)colN0 + wc * 64 + n * 16 + lr;
        const float y = acc[m][n][r];
        const float d = xq + ks[gcol] - 2.0f * y + EPS_F;
        const float v = y * y * __builtin_amdgcn_rcpf(d);
        orow[gcol] = (v + bias[gcol]) * scale;
      }
    }
  }
}

// ------------------------------ launch -------------------------------------

extern "C" void kernel_launch(void* const* d_in, const int* in_sizes, int n_in,
                              void* d_out, int out_size, void* d_ws, size_t ws_size,
                              hipStream_t stream) {
  const float* x     = (const float*)d_in[0];
  const float* w     = (const float*)d_in[1];
  const float* bias  = (const float*)d_in[2];
  const float* alpha = (const float*)d_in[3];
  float* out = (float*)d_out;
  char* ws = (char*)d_ws;

  unsigned short* xbf = (unsigned short*)(ws);
  unsigned short* ktb = (unsigned short*)(ws + 67108864);
  float* xs    = (float*)(ws + 100663296);
  float* ks    = (float*)(ws + 100728832);
  float* kpart = (float*)(ws + 100761600);

  k_conv_x<<<M_DIM, 256, 0, stream>>>(x, xbf, xs);
  if (ws_size >= 100761600ull + (size_t)64 * N_DIM * 4) {
    // fused: kT transpose + 32-row ssq partials (64 blocks), then sum
    k_conv_kT_fused<<<dim3(N_DIM / 32, K_DIM / 32), dim3(32, 8), 0, stream>>>(w, ktb, kpart);
    k_ksq_fin<<<N_DIM / 256, 256, 0, stream>>>(kpart, ks, 64);
  } else {
    k_conv_kT<<<dim3(N_DIM / 32, K_DIM / 32), dim3(32, 8), 0, stream>>>(w, ktb);
    k_ksq_part<<<dim3(N_DIM / 256, 16), 256, 0, stream>>>(w, kpart);
    k_ksq_fin<<<N_DIM / 256, 256, 0, stream>>>(kpart, ks, 16);
  }
  k_gemm<<<(M_DIM / 256) * (N_DIM / 256), 512, 0, stream>>>(xbf, ktb, xs, ks, bias, alpha, out);
}

// Round 6
// 659.563 us; speedup vs baseline: 1.4567x; 1.4567x over previous
//
#include <hip/hip_runtime.h>
#include <hip/hip_bf16.h>
#include <math.h>

// ---------------------------------------------------------------------------
// YatNMN: out = scale * ( y^2/(||x||^2+||w||^2-2y+eps) + bias ), y = x@W
// x:[16384,2048] f32, W:[2048,8192] f32, out f32 [16384,8192].
// R6: 256x128 tile, 8 waves of 64x64 (acc=64 regs -> frag dbuf fits),
// triple-buffered LDS (144KB), full-tile register prefetch, steady-state
// vmcnt(6), 2 phases/tile. Fixes R5's spill (acc 128 left zero headroom).
// Workspace: [0) xbf 64MB | [64M) ktb 32MB | xs | ks | kpart (<=2MB)
// ---------------------------------------------------------------------------

#define EPS_F (1.0f / 137.0f)
#define M_DIM 16384
#define N_DIM 8192
#define K_DIM 2048

typedef __attribute__((ext_vector_type(8))) short short8;
typedef __attribute__((ext_vector_type(4))) float f32x4;

__device__ __forceinline__ unsigned short f2bf(float f) {
  unsigned int u = __float_as_uint(f);
  u += 0x7fffu + ((u >> 16) & 1u);
  return (unsigned short)(u >> 16);
}

typedef __attribute__((address_space(1))) const unsigned int as1_cuint;
typedef __attribute__((address_space(3))) unsigned int as3_uint;

__device__ __forceinline__ void gload16(const void* g, void* lds_wave_base) {
  __builtin_amdgcn_global_load_lds((as1_cuint*)g, (as3_uint*)lds_wave_base, 16, 0, 0);
}

// --------------------------- prologue kernels ------------------------------

__global__ __launch_bounds__(256) void k_conv_x(const float* __restrict__ x,
                                                unsigned short* __restrict__ xbf,
                                                float* __restrict__ xs) {
  const int row = blockIdx.x;
  const int t = threadIdx.x;
  const float4* xr = (const float4*)(x + (size_t)row * K_DIM);
  ushort4* orow = (ushort4*)(xbf + (size_t)row * K_DIM);
  float s = 0.f;
#pragma unroll
  for (int i = 0; i < 2; ++i) {
    float4 v = xr[t + i * 256];
    s += v.x * v.x + v.y * v.y + v.z * v.z + v.w * v.w;
    ushort4 o;
    o.x = f2bf(v.x); o.y = f2bf(v.y); o.z = f2bf(v.z); o.w = f2bf(v.w);
    orow[t + i * 256] = o;
  }
#pragma unroll
  for (int off = 32; off > 0; off >>= 1) s += __shfl_down(s, off, 64);
  __shared__ float red[4];
  if ((t & 63) == 0) red[t >> 6] = s;
  __syncthreads();
  if (t == 0) xs[row] = red[0] + red[1] + red[2] + red[3];
}

// W [K][N] f32 -> W^T [N][K] bf16, fused per-(32-row-block, col) ssq partials.
__global__ __launch_bounds__(256) void k_conv_kT_fused(const float* __restrict__ w,
                                                       unsigned short* __restrict__ bt,
                                                       float* __restrict__ kpart) {
  __shared__ float tile[32][33];
  __shared__ float psum[8][33];
  const int tx = threadIdx.x;
  const int ty = threadIdx.y;
  const int n0 = blockIdx.x * 32;
  const int k0 = blockIdx.y * 32;
  float ss = 0.f;
#pragma unroll
  for (int j = 0; j < 32; j += 8) {
    float v = w[(size_t)(k0 + ty + j) * N_DIM + n0 + tx];
    tile[ty + j][tx] = v;
    ss += v * v;
  }
  psum[ty][tx] = ss;
  __syncthreads();
#pragma unroll
  for (int j = 0; j < 32; j += 8)
    bt[(size_t)(n0 + ty + j) * K_DIM + k0 + tx] = f2bf(tile[tx][ty + j]);
  if (ty == 0) {
    float s = 0.f;
#pragma unroll
    for (int r = 0; r < 8; ++r) s += psum[r][tx];
    kpart[(size_t)(k0 >> 5) * N_DIM + n0 + tx] = s;
  }
}

__global__ __launch_bounds__(256) void k_conv_kT(const float* __restrict__ w,
                                                 unsigned short* __restrict__ bt) {
  __shared__ float tile[32][33];
  const int tx = threadIdx.x;
  const int ty = threadIdx.y;
  const int n0 = blockIdx.x * 32;
  const int k0 = blockIdx.y * 32;
#pragma unroll
  for (int j = 0; j < 32; j += 8)
    tile[ty + j][tx] = w[(size_t)(k0 + ty + j) * N_DIM + n0 + tx];
  __syncthreads();
#pragma unroll
  for (int j = 0; j < 32; j += 8)
    bt[(size_t)(n0 + ty + j) * K_DIM + k0 + tx] = f2bf(tile[tx][ty + j]);
}

__global__ __launch_bounds__(256) void k_ksq_part(const float* __restrict__ w,
                                                  float* __restrict__ kpart) {
  const int col = blockIdx.x * 256 + threadIdx.x;
  const int kb = blockIdx.y;
  float s = 0.f;
#pragma unroll 4
  for (int k = kb * 128; k < kb * 128 + 128; ++k) {
    float v = w[(size_t)k * N_DIM + col];
    s += v * v;
  }
  kpart[kb * N_DIM + col] = s;
}

__global__ __launch_bounds__(256) void k_ksq_fin(const float* __restrict__ kpart,
                                                 float* __restrict__ ks, int nkb) {
  const int col = blockIdx.x * 256 + threadIdx.x;
  float s = 0.f;
  for (int kb = 0; kb < nkb; ++kb) s += kpart[(size_t)kb * N_DIM + col];
  ks[col] = s;
}

// ------------------------------- GEMM 256x128, 3-buf pipeline --------------
// A: xbf [M][K] bf16.  B: ktb [N][K] bf16.  8 waves: wr=wid>>1 (4 M-bands),
// wc=wid&1 (2 N-halves); per-wave out 64x64, acc[4][4] f32x4 = 64 regs.
// LDS: sA 3 bufs x [256][128B] (32KB), sB 3 bufs x [128][128B] (16KB) =
// 144 KiB. XOR swizzle byte_col ^= (row&7)<<4 on ds_read; inverse on the
// global source (gload_lds writes LDS linearly).
// Pipeline (2 phases/tile, tiles tau = 0..31, buf = tau%3):
//   - frags of tile tau+1 ds_read during tau's phases (B at phA, A at phB);
//     consumed a full phase later -> lgkmcnt hides under MFMA.
//   - tile tau+3 staged into buf(tau) during tau's phases (3 calls/phase);
//     buf(tau) was fully consumed by end of tau-1.
//   - vmcnt(6) at end of each tile (before last BAR): 6 newest = current
//     tile's own stage calls; guarantees tile tau+2 landed for tau+1's reads.
//     Never drained to 0 in the loop.

#define MFMA_OP(d, va, vb) \
  d = __builtin_amdgcn_mfma_f32_16x16x32_bf16(va, vb, d, 0, 0, 0)

#define FENCE asm volatile("" ::: "memory")
#define BAR do { FENCE; __builtin_amdgcn_s_barrier(); FENCE; } while (0)
#define VMCNT6  asm volatile("s_waitcnt vmcnt(6)" ::: "memory")
#define VMCNT12 asm volatile("s_waitcnt vmcnt(12)" ::: "memory")

__global__ __launch_bounds__(512, 2) void k_gemm(const unsigned short* __restrict__ A,
                                                 const unsigned short* __restrict__ B,
                                                 const float* __restrict__ xs,
                                                 const float* __restrict__ ks,
                                                 const float* __restrict__ bias,
                                                 const float* __restrict__ alpha,
                                                 float* __restrict__ out) {
  __shared__ __align__(16) char lds[147456];
  char* sA = lds;            // 3 x 32768
  char* sB = lds + 98304;    // 3 x 16384

  const int t = threadIdx.x;
  const int lane = t & 63;
  const int wid = t >> 6;
  const int wr = wid >> 1;  // 0..3 (M band)
  const int wc = wid & 1;   // 0..1 (N half)
  const int lr = lane & 15;
  const int kh = lane >> 4;
  const int swz = (lr & 7) << 4;

  // XCD 2D-chunked swizzle, bijective: 4096 = 8 xcd * 16 chunks * 32.
  // XCD region 16tm x 32tn; chunks of 4tm x 8tn (32 blocks).
  const int bid = blockIdx.x;
  const int xcd = bid & 7;
  const int sub = bid >> 3;    // 0..511
  const int ch  = sub >> 5;    // 0..15
  const int w32 = sub & 31;
  const int tm = ((xcd >> 1) << 4) + ((ch >> 2) << 2) + (w32 >> 3);  // 0..63
  const int tn = ((xcd & 1) << 5) + ((ch & 3) << 3) + (w32 & 7);     // 0..63
  const size_t rowM0 = (size_t)tm * 256;
  const size_t colN0 = (size_t)tn * 128;

  // staging geometry: one gload16 per wave covers 8 rows (1KB linear LDS)
  const int l8 = lane >> 3;
  const int col16 = (lane & 7) ^ (l8 & 7);  // inverse-swizzled 16B slot
  const unsigned short* gA0 = A + (rowM0 + wid * 8 + l8) * K_DIM + col16 * 8;
  const unsigned short* gB0 = B + (colN0 + wid * 8 + l8) * K_DIM + col16 * 8;

// stage 64 rows (s*64..s*64+63) of an A tile / (j*64..) of a B tile
#define STAGE_A(boff, s, ko) \
  gload16(gA0 + (size_t)(s) * 64 * K_DIM + (ko), \
          sA + (boff) + ((s) * 64 + wid * 8) * 128)
#define STAGE_B(boff, j, ko) \
  gload16(gB0 + (size_t)(j) * 64 * K_DIM + (ko), \
          sB + (boff) + ((j) * 64 + wid * 8) * 128)

#define RD_A(boff, m, kk) \
  (*(const short8*)(sA + (boff) + (wr * 64 + (m) * 16 + lr) * 128 + \
                    (((kk) * 64 + kh * 16) ^ swz)))
#define RD_B(boff, n, kk) \
  (*(const short8*)(sB + (boff) + (wc * 64 + (n) * 16 + lr) * 128 + \
                    (((kk) * 64 + kh * 16) ^ swz)))

  f32x4 acc[4][4] = {};
  short8 aX[8], bX[8], aY[8], bY[8];  // [idx] = frag(i, kk) at i*2+kk

#define LOAD_A8(AS, boff) do { \
  AS[0] = RD_A(boff, 0, 0); AS[1] = RD_A(boff, 0, 1); \
  AS[2] = RD_A(boff, 1, 0); AS[3] = RD_A(boff, 1, 1); \
  AS[4] = RD_A(boff, 2, 0); AS[5] = RD_A(boff, 2, 1); \
  AS[6] = RD_A(boff, 3, 0); AS[7] = RD_A(boff, 3, 1); \
} while (0)
#define LOAD_B8(BS, boff) do { \
  BS[0] = RD_B(boff, 0, 0); BS[1] = RD_B(boff, 0, 1); \
  BS[2] = RD_B(boff, 1, 0); BS[3] = RD_B(boff, 1, 1); \
  BS[4] = RD_B(boff, 2, 0); BS[5] = RD_B(boff, 2, 1); \
  BS[6] = RD_B(boff, 3, 0); BS[7] = RD_B(boff, 3, 1); \
} while (0)

// 16 MFMA: m in {mb, mb+1} x 4n x 2kk
#define MFMA16(mb, AS, BS) do { \
  __builtin_amdgcn_s_setprio(1); \
  MFMA_OP(acc[mb][0], AS[(mb)*2], BS[0]); MFMA_OP(acc[mb][1], AS[(mb)*2], BS[2]); \
  MFMA_OP(acc[mb][2], AS[(mb)*2], BS[4]); MFMA_OP(acc[mb][3], AS[(mb)*2], BS[6]); \
  MFMA_OP(acc[(mb)+1][0], AS[(mb)*2+2], BS[0]); MFMA_OP(acc[(mb)+1][1], AS[(mb)*2+2], BS[2]); \
  MFMA_OP(acc[(mb)+1][2], AS[(mb)*2+2], BS[4]); MFMA_OP(acc[(mb)+1][3], AS[(mb)*2+2], BS[6]); \
  MFMA_OP(acc[mb][0], AS[(mb)*2+1], BS[1]); MFMA_OP(acc[mb][1], AS[(mb)*2+1], BS[3]); \
  MFMA_OP(acc[mb][2], AS[(mb)*2+1], BS[5]); MFMA_OP(acc[mb][3], AS[(mb)*2+1], BS[7]); \
  MFMA_OP(acc[(mb)+1][0], AS[(mb)*2+3], BS[1]); MFMA_OP(acc[(mb)+1][1], AS[(mb)*2+3], BS[3]); \
  MFMA_OP(acc[(mb)+1][2], AS[(mb)*2+3], BS[5]); MFMA_OP(acc[(mb)+1][3], AS[(mb)*2+3], BS[7]); \
  __builtin_amdgcn_s_setprio(0); \
} while (0)

  // prologue: stage tiles 0,1,2 into bufs 0,1,2 (18 calls)
  STAGE_A(0, 0, 0); STAGE_A(0, 1, 0); STAGE_A(0, 2, 0); STAGE_A(0, 3, 0);
  STAGE_B(0, 0, 0); STAGE_B(0, 1, 0);
  STAGE_A(32768, 0, 64); STAGE_A(32768, 1, 64); STAGE_A(32768, 2, 64); STAGE_A(32768, 3, 64);
  STAGE_B(16384, 0, 64); STAGE_B(16384, 1, 64);
  STAGE_A(65536, 0, 128); STAGE_A(65536, 1, 128); STAGE_A(65536, 2, 128); STAGE_A(65536, 3, 128);
  STAGE_B(32768, 0, 128); STAGE_B(32768, 1, 128);
  VMCNT12;  // tile0 landed
  BAR;
  LOAD_B8(bX, 0);
  LOAD_A8(aX, 0);
  VMCNT6;   // tile1 landed
  BAR;

  // buf offset rotation (runtime values; frag sets alternate X/Y per tile)
  int cA0 = 0, cA1 = 32768, cA2 = 65536;
  int cB0 = 0, cB1 = 16384, cB2 = 32768;

#pragma unroll 1
  for (int it = 0; it < 16; ++it) {
    const int koE = (it <= 14) ? (2 * it + 3) * 64 : 0;  // tile 2it+3 (clamped)
    const int koO = (it <= 13) ? (2 * it + 4) * 64 : 0;  // tile 2it+4 (clamped)
    // ---- tile 2it (frags X; prefetch Y from buf c1; stage 2it+3 -> c0) ----
    LOAD_B8(bY, cB1);
    STAGE_A(cA0, 0, koE); STAGE_A(cA0, 1, koE); STAGE_A(cA0, 2, koE);
    BAR; MFMA16(0, aX, bX); BAR;
    LOAD_A8(aY, cA1);
    STAGE_A(cA0, 3, koE); STAGE_B(cB0, 0, koE); STAGE_B(cB0, 1, koE);
    BAR; MFMA16(2, aX, bX); VMCNT6; BAR;
    // ---- tile 2it+1 (frags Y; prefetch X from buf c2; stage 2it+4 -> c1) --
    LOAD_B8(bX, cB2);
    STAGE_A(cA1, 0, koO); STAGE_A(cA1, 1, koO); STAGE_A(cA1, 2, koO);
    BAR; MFMA16(0, aY, bY); BAR;
    LOAD_A8(aX, cA2);
    STAGE_A(cA1, 3, koO); STAGE_B(cB1, 0, koO); STAGE_B(cB1, 1, koO);
    BAR; MFMA16(2, aY, bY); VMCNT6; BAR;
    // rotate bufs forward by 2: (c0,c1,c2) = (c2,c0,c1)
    int tA = cA2; cA2 = cA1; cA1 = cA0; cA0 = tA;
    int tB = cB2; cB2 = cB1; cB1 = cB0; cB0 = tB;
  }

  asm volatile("s_waitcnt vmcnt(0)" ::: "memory");

  // fused Yat epilogue. C/D: col = lane&15 (N), row = (lane>>4)*4 + reg (M).
  const float scale = powf(sqrtf(8192.0f) / log1pf(8192.0f), alpha[0]);
#pragma unroll
  for (int m = 0; m < 4; ++m) {
#pragma unroll
    for (int r = 0; r < 4; ++r) {
      const size_t grow = rowM0 + wr * 64 + m * 16 + kh * 4 + r;
      const float xq = xs[grow];
      float* orow = out + grow * N_DIM;
#pragma unroll
      for (int n = 0; n < 4; ++n) {
        const int gcol = (int)colN0 + wc * 64 + n * 16 + lr;
        const float y = acc[m][n][r];
        const float d = xq + ks[gcol] - 2.0f * y + EPS_F;
        const float v = y * y * __builtin_amdgcn_rcpf(d);
        orow[gcol] = (v + bias[gcol]) * scale;
      }
    }
  }
}

// ------------------------------ launch -------------------------------------

extern "C" void kernel_launch(void* const* d_in, const int* in_sizes, int n_in,
                              void* d_out, int out_size, void* d_ws, size_t ws_size,
                              hipStream_t stream) {
  const float* x     = (const float*)d_in[0];
  const float* w     = (const float*)d_in[1];
  const float* bias  = (const float*)d_in[2];
  const float* alpha = (const float*)d_in[3];
  float* out = (float*)d_out;
  char* ws = (char*)d_ws;

  unsigned short* xbf = (unsigned short*)(ws);
  unsigned short* ktb = (unsigned short*)(ws + 67108864);
  float* xs    = (float*)(ws + 100663296);
  float* ks    = (float*)(ws + 100728832);
  float* kpart = (float*)(ws + 100761600);

  k_conv_x<<<M_DIM, 256, 0, stream>>>(x, xbf, xs);
  if (ws_size >= 100761600ull + (size_t)64 * N_DIM * 4) {
    k_conv_kT_fused<<<dim3(N_DIM / 32, K_DIM / 32), dim3(32, 8), 0, stream>>>(w, ktb, kpart);
    k_ksq_fin<<<N_DIM / 256, 256, 0, stream>>>(kpart, ks, 64);
  } else {
    k_conv_kT<<<dim3(N_DIM / 32, K_DIM / 32), dim3(32, 8), 0, stream>>>(w, ktb);
    k_ksq_part<<<dim3(N_DIM / 256, 16), 256, 0, stream>>>(w, kpart);
    k_ksq_fin<<<N_DIM / 256, 256, 0, stream>>>(kpart, ks, 16);
  }
  k_gemm<<<(M_DIM / 256) * (N_DIM / 128), 512, 0, stream>>>(xbf, ktb, xs, ks, bias, alpha, out);
}

// Round 7
// 576.841 us; speedup vs baseline: 1.6656x; 1.1434x over previous
//
#include <hip/hip_runtime.h>
#include <hip/hip_bf16.h>
#include <math.h>

// ---------------------------------------------------------------------------
// YatNMN: out = scale * ( y^2/(||x||^2+||w||^2-2y+eps) + bias ), y = x@W
// x:[16384,2048] f32, W:[2048,8192] f32, out f32 [16384,8192].
// R7 = R4 geometry (256x256, 8 waves x 128x64, LDS dbuf 128KB, 2D XCD
// chunking) with m201-exact emission: uniform read/compute regions, bare
// s_barrier, explicit lgkmcnt(0)+sched_barrier(0) before each MFMA cluster,
// counted vmcnt(6) once per K-tile, no memory-clobber fences on barriers.
// Workspace: [0) xbf 64MB | [64M) ktb 32MB | xs | ks | kpart (<=2MB)
// ---------------------------------------------------------------------------

#define EPS_F (1.0f / 137.0f)
#define M_DIM 16384
#define N_DIM 8192
#define K_DIM 2048

typedef __attribute__((ext_vector_type(8))) short short8;
typedef __attribute__((ext_vector_type(4))) float f32x4;

__device__ __forceinline__ unsigned short f2bf(float f) {
  unsigned int u = __float_as_uint(f);
  u += 0x7fffu + ((u >> 16) & 1u);
  return (unsigned short)(u >> 16);
}

typedef __attribute__((address_space(1))) const unsigned int as1_cuint;
typedef __attribute__((address_space(3))) unsigned int as3_uint;

__device__ __forceinline__ void gload16(const void* g, void* lds_wave_base) {
  __builtin_amdgcn_global_load_lds((as1_cuint*)g, (as3_uint*)lds_wave_base, 16, 0, 0);
}

// --------------------------- prologue kernels ------------------------------

__global__ __launch_bounds__(256) void k_conv_x(const float* __restrict__ x,
                                                unsigned short* __restrict__ xbf,
                                                float* __restrict__ xs) {
  const int row = blockIdx.x;
  const int t = threadIdx.x;
  const float4* xr = (const float4*)(x + (size_t)row * K_DIM);
  ushort4* orow = (ushort4*)(xbf + (size_t)row * K_DIM);
  float s = 0.f;
#pragma unroll
  for (int i = 0; i < 2; ++i) {
    float4 v = xr[t + i * 256];
    s += v.x * v.x + v.y * v.y + v.z * v.z + v.w * v.w;
    ushort4 o;
    o.x = f2bf(v.x); o.y = f2bf(v.y); o.z = f2bf(v.z); o.w = f2bf(v.w);
    orow[t + i * 256] = o;
  }
#pragma unroll
  for (int off = 32; off > 0; off >>= 1) s += __shfl_down(s, off, 64);
  __shared__ float red[4];
  if ((t & 63) == 0) red[t >> 6] = s;
  __syncthreads();
  if (t == 0) xs[row] = red[0] + red[1] + red[2] + red[3];
}

// W [K][N] f32 -> W^T [N][K] bf16, fused per-(32-row-block, col) ssq partials.
__global__ __launch_bounds__(256) void k_conv_kT_fused(const float* __restrict__ w,
                                                       unsigned short* __restrict__ bt,
                                                       float* __restrict__ kpart) {
  __shared__ float tile[32][33];
  __shared__ float psum[8][33];
  const int tx = threadIdx.x;
  const int ty = threadIdx.y;
  const int n0 = blockIdx.x * 32;
  const int k0 = blockIdx.y * 32;
  float ss = 0.f;
#pragma unroll
  for (int j = 0; j < 32; j += 8) {
    float v = w[(size_t)(k0 + ty + j) * N_DIM + n0 + tx];
    tile[ty + j][tx] = v;
    ss += v * v;
  }
  psum[ty][tx] = ss;
  __syncthreads();
#pragma unroll
  for (int j = 0; j < 32; j += 8)
    bt[(size_t)(n0 + ty + j) * K_DIM + k0 + tx] = f2bf(tile[tx][ty + j]);
  if (ty == 0) {
    float s = 0.f;
#pragma unroll
    for (int r = 0; r < 8; ++r) s += psum[r][tx];
    kpart[(size_t)(k0 >> 5) * N_DIM + n0 + tx] = s;
  }
}

__global__ __launch_bounds__(256) void k_conv_kT(const float* __restrict__ w,
                                                 unsigned short* __restrict__ bt) {
  __shared__ float tile[32][33];
  const int tx = threadIdx.x;
  const int ty = threadIdx.y;
  const int n0 = blockIdx.x * 32;
  const int k0 = blockIdx.y * 32;
#pragma unroll
  for (int j = 0; j < 32; j += 8)
    tile[ty + j][tx] = w[(size_t)(k0 + ty + j) * N_DIM + n0 + tx];
  __syncthreads();
#pragma unroll
  for (int j = 0; j < 32; j += 8)
    bt[(size_t)(n0 + ty + j) * K_DIM + k0 + tx] = f2bf(tile[tx][ty + j]);
}

__global__ __launch_bounds__(256) void k_ksq_part(const float* __restrict__ w,
                                                  float* __restrict__ kpart) {
  const int col = blockIdx.x * 256 + threadIdx.x;
  const int kb = blockIdx.y;
  float s = 0.f;
#pragma unroll 4
  for (int k = kb * 128; k < kb * 128 + 128; ++k) {
    float v = w[(size_t)k * N_DIM + col];
    s += v * v;
  }
  kpart[kb * N_DIM + col] = s;
}

__global__ __launch_bounds__(256) void k_ksq_fin(const float* __restrict__ kpart,
                                                 float* __restrict__ ks, int nkb) {
  const int col = blockIdx.x * 256 + threadIdx.x;
  float s = 0.f;
  for (int kb = 0; kb < nkb; ++kb) s += kpart[(size_t)kb * N_DIM + col];
  ks[col] = s;
}

// ------------------------------- GEMM 256x256 ------------------------------
// A: xbf [M][K] bf16.  B: ktb [N][K] bf16.  8 waves: wr=wid>>2 (M), wc=wid&3.
// LDS: sA[2][256][128B], sB[2][256][128B] = 128 KiB. XOR swizzle
//   byte_col ^= (row&7)<<4 on ds_read; inverse pre-applied to the global
//   source of global_load_lds (LDS written linearly).
// Region schedule per K-tile tau (buf b = tau&1), 4 {R,C} region pairs:
//   R0: finish-stage tile tau+1 (2 calls) + 12 ds_reads (8 B, A m01)
//   C0: barrier; lgkmcnt(0); sched_barrier; 16 MFMA (m01); barrier
//   R1..R3: 4 A-reads (m23/m45/m67) + 2 stage calls of tile tau+2
//   C3 additionally: vmcnt(6) (drains tile tau+1's last stages; keeps
//   tau+2's 6 in flight). Counted waits only; no drain-to-0 in the loop.
// WAR safety: each stage call targets LDS rows whose reads completed at
// least one barrier earlier (stripe s staged at R(s+1); B staged R1+ after
// R0's B-reads; leftover stripe3+B3 staged in next tile's R0 -> other buf).

#define MFMA_OP(d, va, vb) \
  d = __builtin_amdgcn_mfma_f32_16x16x32_bf16(va, vb, d, 0, 0, 0)

#define BARRIER __builtin_amdgcn_s_barrier()
#define LGKM0_SGB do { \
  asm volatile("s_waitcnt lgkmcnt(0)" ::: "memory"); \
  __builtin_amdgcn_sched_barrier(0); \
} while (0)
#define VMCNT6 asm volatile("s_waitcnt vmcnt(6)" ::: "memory")

__global__ __launch_bounds__(512) void k_gemm(const unsigned short* __restrict__ A,
                                              const unsigned short* __restrict__ B,
                                              const float* __restrict__ xs,
                                              const float* __restrict__ ks,
                                              const float* __restrict__ bias,
                                              const float* __restrict__ alpha,
                                              float* __restrict__ out) {
  __shared__ __align__(16) char lds[131072];
  char* sA = lds;
  char* sB = lds + 65536;

  const int t = threadIdx.x;
  const int lane = t & 63;
  const int wid = t >> 6;
  const int wr = wid >> 2;  // 0..1 (M)
  const int wc = wid & 3;   // 0..3 (N)
  const int lr = lane & 15;
  const int kh = lane >> 4;
  const int swz = (lr & 7) << 4;

  // 2D-chunked XCD swizzle (bijective: 2048 = 8 xcd * 8 chunks * 32).
  const int bid = blockIdx.x;
  const int xcd = bid & 7;
  const int sub = bid >> 3;
  const int c   = sub >> 5;
  const int tm = ((xcd >> 1) << 4) + ((c >> 1) << 2) + ((sub >> 3) & 3);
  const int tn = ((xcd & 1) << 4) + ((c & 1) << 3) + (sub & 7);
  const size_t rowM0 = (size_t)tm * 256;
  const size_t colN0 = (size_t)tn * 256;

  const int l8 = lane >> 3;
  const int col16 = (lane & 7) ^ (l8 & 7);  // inverse-swizzled 16B slot
  const int rA_base = (wid < 4) ? wid * 8 : 128 + (wid - 4) * 8;
  const unsigned short* gA0 = A + (rowM0 + rA_base + l8) * K_DIM + col16 * 8;
  const unsigned short* gB0 = B + (colN0 + wid * 8 + l8) * K_DIM + col16 * 8;

#define STAGE_A(b, s, ko) \
  gload16(gA0 + (size_t)(s) * 32 * K_DIM + (ko), \
          sA + (b) * 32768 + (rA_base + (s) * 32) * 128)
#define STAGE_B(b, j, ko) \
  gload16(gB0 + (size_t)(j) * 64 * K_DIM + (ko), \
          sB + (b) * 32768 + ((j) * 64 + wid * 8) * 128)

#define RD_A(b, m, kk) \
  (*(const short8*)(sA + (b) * 32768 + (wr * 128 + (m) * 16 + lr) * 128 + \
                    (((kk) * 64 + kh * 16) ^ swz)))
#define RD_B(b, n, kk) \
  (*(const short8*)(sB + (b) * 32768 + (wc * 64 + (n) * 16 + lr) * 128 + \
                    (((kk) * 64 + kh * 16) ^ swz)))

  f32x4 acc[8][4] = {};
  short8 a0, a1, a2, a3;  // current pair: m_lo kk0/kk1, m_hi kk0/kk1
  short8 b[8];            // b[n]=kk0, b[4+n]=kk1

#define LOAD_A4(bf, mb) do { \
  a0 = RD_A(bf, mb, 0); a1 = RD_A(bf, mb, 1); \
  a2 = RD_A(bf, (mb)+1, 0); a3 = RD_A(bf, (mb)+1, 1); \
} while (0)
#define LOAD_B8(bf) do { \
  b[0] = RD_B(bf, 0, 0); b[1] = RD_B(bf, 1, 0); b[2] = RD_B(bf, 2, 0); b[3] = RD_B(bf, 3, 0); \
  b[4] = RD_B(bf, 0, 1); b[5] = RD_B(bf, 1, 1); b[6] = RD_B(bf, 2, 1); b[7] = RD_B(bf, 3, 1); \
} while (0)

#define MFMA16(mb) do { \
  __builtin_amdgcn_s_setprio(1); \
  MFMA_OP(acc[mb][0], a0, b[0]); MFMA_OP(acc[mb][1], a0, b[1]); \
  MFMA_OP(acc[mb][2], a0, b[2]); MFMA_OP(acc[mb][3], a0, b[3]); \
  MFMA_OP(acc[(mb)+1][0], a2, b[0]); MFMA_OP(acc[(mb)+1][1], a2, b[1]); \
  MFMA_OP(acc[(mb)+1][2], a2, b[2]); MFMA_OP(acc[(mb)+1][3], a2, b[3]); \
  MFMA_OP(acc[mb][0], a1, b[4]); MFMA_OP(acc[mb][1], a1, b[5]); \
  MFMA_OP(acc[mb][2], a1, b[6]); MFMA_OP(acc[mb][3], a1, b[7]); \
  MFMA_OP(acc[(mb)+1][0], a3, b[4]); MFMA_OP(acc[(mb)+1][1], a3, b[5]); \
  MFMA_OP(acc[(mb)+1][2], a3, b[6]); MFMA_OP(acc[(mb)+1][3], a3, b[7]); \
  __builtin_amdgcn_s_setprio(0); \
} while (0)

// one K-tile = 4 {R,C} pairs. RF = finish-stage pair for tile tau+1 (in R0);
// S1..S3 = stage pairs for tile tau+2 (R1..R3).
#define TILE(bf, RF, S1, S2, S3) do { \
  RF; \
  LOAD_B8(bf); LOAD_A4(bf, 0); \
  BARRIER; LGKM0_SGB; MFMA16(0); BARRIER; \
  LOAD_A4(bf, 2); S1; \
  BARRIER; LGKM0_SGB; MFMA16(2); BARRIER; \
  LOAD_A4(bf, 4); S2; \
  BARRIER; LGKM0_SGB; MFMA16(4); BARRIER; \
  LOAD_A4(bf, 6); S3; \
  BARRIER; LGKM0_SGB; MFMA16(6); VMCNT6; BARRIER; \
} while (0)

  // prologue: T0 full (8 calls) -> buf0; T1 stripes 0-2 + B0-2 (6) -> buf1
  STAGE_A(0, 0, 0); STAGE_B(0, 0, 0);
  STAGE_A(0, 1, 0); STAGE_B(0, 1, 0);
  STAGE_A(0, 2, 0); STAGE_B(0, 2, 0);
  STAGE_A(0, 3, 0); STAGE_B(0, 3, 0);
  STAGE_A(1, 0, 64); STAGE_B(1, 0, 64);
  STAGE_A(1, 1, 64); STAGE_B(1, 1, 64);
  STAGE_A(1, 2, 64); STAGE_B(1, 2, 64);
  VMCNT6;  // T0's 8 landed; T1's 6 in flight
  BARRIER;

#pragma unroll 1
  for (int it = 0; it < 16; ++it) {
    const int kT1 = it * 128 + 64;                    // tile 2it+1 (real)
    const int kS0 = (it < 15) ? it * 128 + 128 : 0;   // tile 2it+2 (clamped)
    const int kS1 = (it < 15) ? it * 128 + 192 : 0;   // tile 2it+3 (clamped)
    // even tile 2it (buf0): finish T1, stage T2 -> buf0
    TILE(0,
         (STAGE_A(1, 3, kT1), STAGE_B(1, 3, kT1)),
         (STAGE_A(0, 0, kS0), STAGE_B(0, 0, kS0)),
         (STAGE_A(0, 1, kS0), STAGE_B(0, 1, kS0)),
         (STAGE_A(0, 2, kS0), STAGE_B(0, 2, kS0)));
    // odd tile 2it+1 (buf1): finish T2, stage T3 -> buf1
    TILE(1,
         (STAGE_A(0, 3, kS0), STAGE_B(0, 3, kS0)),
         (STAGE_A(1, 0, kS1), STAGE_B(1, 0, kS1)),
         (STAGE_A(1, 1, kS1), STAGE_B(1, 1, kS1)),
         (STAGE_A(1, 2, kS1), STAGE_B(1, 2, kS1)));
  }

  asm volatile("s_waitcnt vmcnt(0)" ::: "memory");

  // fused Yat epilogue. C/D: col = lane&15 (N), row = (lane>>4)*4 + reg (M).
  const float scale = powf(sqrtf(8192.0f) / log1pf(8192.0f), alpha[0]);
#pragma unroll
  for (int m = 0; m < 8; ++m) {
#pragma unroll
    for (int r = 0; r < 4; ++r) {
      const size_t grow = rowM0 + wr * 128 + m * 16 + kh * 4 + r;
      const float xq = xs[grow];
      float* orow = out + grow * N_DIM;
#pragma unroll
      for (int n = 0; n < 4; ++n) {
        const int gcol = (int)colN0 + wc * 64 + n * 16 + lr;
        const float y = acc[m][n][r];
        const float d = xq + ks[gcol] - 2.0f * y + EPS_F;
        const float v = y * y * __builtin_amdgcn_rcpf(d);
        orow[gcol] = (v + bias[gcol]) * scale;
      }
    }
  }
}

// ------------------------------ launch -------------------------------------

extern "C" void kernel_launch(void* const* d_in, const int* in_sizes, int n_in,
                              void* d_out, int out_size, void* d_ws, size_t ws_size,
                              hipStream_t stream) {
  const float* x     = (const float*)d_in[0];
  const float* w     = (const float*)d_in[1];
  const float* bias  = (const float*)d_in[2];
  const float* alpha = (const float*)d_in[3];
  float* out = (float*)d_out;
  char* ws = (char*)d_ws;

  unsigned short* xbf = (unsigned short*)(ws);
  unsigned short* ktb = (unsigned short*)(ws + 67108864);
  float* xs    = (float*)(ws + 100663296);
  float* ks    = (float*)(ws + 100728832);
  float* kpart = (float*)(ws + 100761600);

  k_conv_x<<<M_DIM, 256, 0, stream>>>(x, xbf, xs);
  if (ws_size >= 100761600ull + (size_t)64 * N_DIM * 4) {
    k_conv_kT_fused<<<dim3(N_DIM / 32, K_DIM / 32), dim3(32, 8), 0, stream>>>(w, ktb, kpart);
    k_ksq_fin<<<N_DIM / 256, 256, 0, stream>>>(kpart, ks, 64);
  } else {
    k_conv_kT<<<dim3(N_DIM / 32, K_DIM / 32), dim3(32, 8), 0, stream>>>(w, ktb);
    k_ksq_part<<<dim3(N_DIM / 256, 16), 256, 0, stream>>>(w, kpart);
    k_ksq_fin<<<N_DIM / 256, 256, 0, stream>>>(kpart, ks, 16);
  }
  k_gemm<<<(M_DIM / 256) * (N_DIM / 256), 512, 0, stream>>>(xbf, ktb, xs, ks, bias, alpha, out);
}